// Round 4
// baseline (2133.279 us; speedup 1.0000x reference)
//
#include <hip/hip_runtime.h>
#include <hip/hip_bf16.h>

typedef _Float16 half8  __attribute__((ext_vector_type(8)));
typedef _Float16 half4_t __attribute__((ext_vector_type(4)));
typedef float    floatx4 __attribute__((ext_vector_type(4)));
typedef int      intx4   __attribute__((ext_vector_type(4)));

#define B_DIM   16384
#define IN_D    2048
#define HV_D    8192
#define NC      1000
#define NCP     1024
#define SCORES_N (B_DIM * NC)

// async global->LDS, 16B per lane; LDS side is wave-uniform base + lane*16
#define GLD16(gp, lp) __builtin_amdgcn_global_load_lds( \
    (const __attribute__((address_space(1))) void*)(gp), \
    (__attribute__((address_space(3))) void*)(lp), 16, 0, 0)

// ---------- P1: Dekker split x (fp32) -> x_hi + x_lo (fp16), exact vs fp32 ----------
__global__ void k_split(const float* __restrict__ x, _Float16* __restrict__ xh,
                        _Float16* __restrict__ xl) {
    size_t i = (size_t)blockIdx.x * 256 + threadIdx.x;
    floatx4 v = ((const floatx4*)x)[i];
    half4_t h, l;
#pragma unroll
    for (int j = 0; j < 4; ++j) {
        _Float16 hh = (_Float16)v[j];
        h[j] = hh;
        l[j] = (_Float16)(v[j] - (float)hh);
    }
    ((half4_t*)xh)[i] = h;
    ((half4_t*)xl)[i] = l;
}

// ---------- P2: proj [K=2048][N=8192] fp32 -> projT [N][K] fp16 (LDS-tiled) ----------
__global__ void k_transpose_proj(const float* __restrict__ p, _Float16* __restrict__ pT) {
    __shared__ float tile[64][65];
    const int t = threadIdx.x;
    const int nt = blockIdx.x * 64;
    const int kt = blockIdx.y * 64;
    const int tr = t >> 4, tc = (t & 15) * 4;
#pragma unroll
    for (int s = 0; s < 4; ++s) {
        int r = tr + s * 16;
        floatx4 v = *(const floatx4*)&p[(size_t)(kt + r) * HV_D + nt + tc];
        tile[r][tc] = v[0]; tile[r][tc + 1] = v[1];
        tile[r][tc + 2] = v[2]; tile[r][tc + 3] = v[3];
    }
    __syncthreads();
#pragma unroll
    for (int s = 0; s < 4; ++s) {
        int rn = tr + s * 16;
        half4_t o;
#pragma unroll
        for (int j = 0; j < 4; ++j) o[j] = (_Float16)tile[tc + j][rn];
        *(half4_t*)&pT[(size_t)(nt + rn) * IN_D + kt + tc] = o;
    }
}

// ---------- P3: class_hv [8192][1000] fp32 -> classT [1024][8192] i8 ----------
__global__ void k_pack_class(const float* __restrict__ c, signed char* __restrict__ cT) {
    __shared__ signed char tile[64][68];
    const int t = threadIdx.x;
    const int nt = blockIdx.x * 64;
    const int kt = blockIdx.y * 64;
    const int nl = t & 63;
    const int n = nt + nl;
#pragma unroll
    for (int s = 0; s < 16; ++s) {
        const int kl = s * 4 + (t >> 6);
        signed char v = 0;
        if (n < NC) {
            float f = c[(size_t)(kt + kl) * NC + n];
            v = (f >= 0.f) ? (signed char)1 : (signed char)-1;
        }
        tile[kl][nl] = v;
    }
    __syncthreads();
    const int wn = t >> 2;
    const int wk = (t & 3) * 16;
    intx4 o;
    signed char* ob = (signed char*)&o;
#pragma unroll
    for (int j = 0; j < 16; ++j) ob[j] = tile[wk + j][wn];
    *(intx4*)&cT[(size_t)(nt + wn) * HV_D + kt + wk] = o;
}

// ---------- G1: hv = x@proj, fp16 hi/lo split, 8-PHASE counted-vmcnt schedule ----------
// BM=128 BN=256 BK=64, 8 waves (2M x 4N), wave tile 64x64, LDS 2x(16+16+32)=128KB dbuf.
// Per K-tile: 4 quadrant phases (mh,nh); each phase: 12 ds_read_b128 + 2 GLD16 stage
// issues + counted vmcnt (6/8, never 0 in loop) + raw s_barrier + setprio'd 16 MFMA.
// Staging parts match quadrant release sets: A round i covers rows {i*32..}U{64+i*32..};
// B part p covers the nh=p row sets. Issue schedule: p0:(t+1)A1 p1:(t+1)B1 p2:(t+2)A0
// p3:(t+2)B0. vmcnt(6)@p0 protects p1 reads; vmcnt(8)@p3 protects next tile's p0.
// Cross-wave safety: every counted wait precedes the phase's first s_barrier; every
// consumer ds_read follows the prior phase's closing barrier.
// Per-element accumulation order (hi k0, lo k0, hi k1, lo k1) == proven kernel, bit-exact.
__launch_bounds__(512, 2)
__global__ void k_gemm1(const _Float16* __restrict__ xh, const _Float16* __restrict__ xl,
                        const _Float16* __restrict__ pT,
                        float* __restrict__ hv_out, signed char* __restrict__ hvb) {
    __shared__ _Float16 sAh[2][128 * 64];   // 2 x 16 KB
    __shared__ _Float16 sAl[2][128 * 64];   // 2 x 16 KB
    __shared__ _Float16 sB [2][256 * 64];   // 2 x 32 KB  => 128 KB total
    const int t = threadIdx.x;
    const int w = t >> 6, l = t & 63;
    const int m0 = blockIdx.y * 128, n0 = blockIdx.x * 256;
    const int wm = (w >> 2) * 64, wn = (w & 3) * 64;
    const int lm = l & 15, kq = l >> 4;

    // staging map: 512 threads x 16B = 8KB = one 64-row round (rows split {0-31}U{64-95} style)
    const int arow  = (w & 3) * 8 + (l >> 3) + (w >> 2) * 64;
    const int gcol  = ((l & 7) ^ (l >> 3)) * 8;      // swizzled global chunk (f16 units)
    const int sbyte = arow * 128 + (l & 7) * 16;     // linear-in-lane LDS byte offset
    const size_t aBase = (size_t)(m0 + arow) * IN_D + gcol;
    const size_t bBase = (size_t)(n0 + arow) * IN_D + gcol;

    // LDS->frag read swizzle slots (row&7 == lm&7 for all frag rows)
    const int csw0 = ((kq)     ^ (lm & 7)) * 8;
    const int csw1 = ((kq + 4) ^ (lm & 7)) * 8;

    floatx4 acc[4][4] = {};

#define STAGE_A(buf, i, kt) do { \
    const size_t g_ = aBase + (size_t)((i) * 32 * IN_D) + (size_t)((kt) * 64); \
    GLD16(xh + g_, (char*)&sAh[buf][0] + (i) * 4096 + sbyte); \
    GLD16(xl + g_, (char*)&sAl[buf][0] + (i) * 4096 + sbyte); \
} while (0)

#define STAGE_B2(buf, p, kt) do { \
    const size_t g_ = bBase + (size_t)((p) * 32 * IN_D) + (size_t)((kt) * 64); \
    GLD16(pT + g_,                       (char*)&sB[buf][0] + (p) * 4096 + sbyte); \
    GLD16(pT + g_ + (size_t)(128 * IN_D), (char*)&sB[buf][0] + 16384 + (p) * 4096 + sbyte); \
} while (0)

#define VM6 asm volatile("s_waitcnt vmcnt(6)" ::: "memory")
#define VM8 asm volatile("s_waitcnt vmcnt(8)" ::: "memory")
#define VM4 asm volatile("s_waitcnt vmcnt(4)" ::: "memory")
#define VM0 asm volatile("s_waitcnt vmcnt(0)" ::: "memory")
#define VMNOP do {} while (0)

#define MM(A_, B_, ci, cj) \
    acc[ci][cj] = __builtin_amdgcn_mfma_f32_16x16x32_f16(A_, B_, acc[ci][cj], 0, 0, 0)

#define PHASE(buf, mh, nh, ISSUE_STMT, WAIT_STMT) do { \
    const int ra0 = (wm + (mh) * 32      + lm) * 64; \
    const int ra1 = (wm + (mh) * 32 + 16 + lm) * 64; \
    const int rb0 = (wn + (nh) * 32      + lm) * 64; \
    const int rb1 = (wn + (nh) * 32 + 16 + lm) * 64; \
    half8 aH00 = *(const half8*)&sAh[buf][ra0 + csw0]; \
    half8 aH01 = *(const half8*)&sAh[buf][ra0 + csw1]; \
    half8 aH10 = *(const half8*)&sAh[buf][ra1 + csw0]; \
    half8 aH11 = *(const half8*)&sAh[buf][ra1 + csw1]; \
    half8 aL00 = *(const half8*)&sAl[buf][ra0 + csw0]; \
    half8 aL01 = *(const half8*)&sAl[buf][ra0 + csw1]; \
    half8 aL10 = *(const half8*)&sAl[buf][ra1 + csw0]; \
    half8 aL11 = *(const half8*)&sAl[buf][ra1 + csw1]; \
    half8 b00  = *(const half8*)&sB[buf][rb0 + csw0]; \
    half8 b01  = *(const half8*)&sB[buf][rb0 + csw1]; \
    half8 b10  = *(const half8*)&sB[buf][rb1 + csw0]; \
    half8 b11  = *(const half8*)&sB[buf][rb1 + csw1]; \
    ISSUE_STMT; \
    WAIT_STMT; \
    __builtin_amdgcn_sched_barrier(0); \
    __builtin_amdgcn_s_barrier(); \
    __builtin_amdgcn_sched_barrier(0); \
    __builtin_amdgcn_s_setprio(1); \
    MM(aH00, b00, (mh)*2+0, (nh)*2+0); MM(aL00, b00, (mh)*2+0, (nh)*2+0); \
    MM(aH01, b01, (mh)*2+0, (nh)*2+0); MM(aL01, b01, (mh)*2+0, (nh)*2+0); \
    MM(aH00, b10, (mh)*2+0, (nh)*2+1); MM(aL00, b10, (mh)*2+0, (nh)*2+1); \
    MM(aH01, b11, (mh)*2+0, (nh)*2+1); MM(aL01, b11, (mh)*2+0, (nh)*2+1); \
    MM(aH10, b00, (mh)*2+1, (nh)*2+0); MM(aL10, b00, (mh)*2+1, (nh)*2+0); \
    MM(aH11, b01, (mh)*2+1, (nh)*2+0); MM(aL11, b01, (mh)*2+1, (nh)*2+0); \
    MM(aH10, b10, (mh)*2+1, (nh)*2+1); MM(aL10, b10, (mh)*2+1, (nh)*2+1); \
    MM(aH11, b11, (mh)*2+1, (nh)*2+1); MM(aL11, b11, (mh)*2+1, (nh)*2+1); \
    __builtin_amdgcn_s_setprio(0); \
    __builtin_amdgcn_sched_barrier(0); \
    __builtin_amdgcn_s_barrier(); \
    __builtin_amdgcn_sched_barrier(0); \
} while (0)

    // ---- prologue: tile0 full into buf0; tile1 A0,B0 into buf1 (12 loads/thread) ----
    STAGE_A(0, 0, 0); STAGE_A(0, 1, 0);
    STAGE_B2(0, 0, 0); STAGE_B2(0, 1, 0);
    STAGE_A(1, 0, 1);
    STAGE_B2(1, 0, 1);
    VM4;   // tile0's 8 landed; tile1's 4 in flight
    __builtin_amdgcn_sched_barrier(0);
    __builtin_amdgcn_s_barrier();
    __builtin_amdgcn_sched_barrier(0);

    // ---- main loop: tiles 0..29 (even->buf0, odd->buf1), T=32 total ----
#pragma unroll 1
    for (int it = 0; it < 15; ++it) {
        const int te = 2 * it;
        // even tile te (buf0)
        PHASE(0, 0, 0, STAGE_A (1, 1, te + 1), VM6);
        PHASE(0, 0, 1, STAGE_B2(1, 1, te + 1), VMNOP);
        PHASE(0, 1, 0, STAGE_A (0, 0, te + 2), VMNOP);
        PHASE(0, 1, 1, STAGE_B2(0, 0, te + 2), VM8);
        // odd tile te+1 (buf1)
        PHASE(1, 0, 0, STAGE_A (0, 1, te + 2), VM6);
        PHASE(1, 0, 1, STAGE_B2(0, 1, te + 2), VMNOP);
        PHASE(1, 1, 0, STAGE_A (1, 0, te + 3), VMNOP);
        PHASE(1, 1, 1, STAGE_B2(1, 0, te + 3), VM8);
    }

    // ---- tail: tile 30 (buf0) and tile 31 (buf1) ----
    PHASE(0, 0, 0, STAGE_A (1, 1, 31), VM6);
    PHASE(0, 0, 1, STAGE_B2(1, 1, 31), VMNOP);
    PHASE(0, 1, 0, VMNOP, VMNOP);
    PHASE(0, 1, 1, VMNOP, VM4);
    PHASE(1, 0, 0, VMNOP, VM0);
    PHASE(1, 0, 1, VMNOP, VMNOP);
    PHASE(1, 1, 0, VMNOP, VMNOP);
    PHASE(1, 1, 1, VMNOP, VMNOP);

    // ---- epilogue: C/D layout col=lane&15, row=(lane>>4)*4+reg; plain stores ----
#pragma unroll
    for (int ms = 0; ms < 4; ++ms) {
#pragma unroll
        for (int ns = 0; ns < 4; ++ns) {
            const int m = m0 + wm + ms * 16 + kq * 4;
            const int n = n0 + wn + ns * 16 + lm;
#pragma unroll
            for (int r = 0; r < 4; ++r) {
                const int pos = (acc[ms][ns][r] >= 0.f);
                const size_t o = (size_t)(m + r) * HV_D + n;
                hv_out[o] = pos ? 1.f : -1.f;
                hvb[o] = (signed char)(pos ? 1 : -1);
            }
        }
    }
#undef PHASE
#undef MM
#undef STAGE_A
#undef STAGE_B2
}

// ---------- G2: scores = hv_bin @ class_hv, exact in i8 (K=8192) ----------
// R2 structure verbatim (measured-neutral): 64x256 block, BK=128, 40KB LDS,
// 4 blocks/CU, wave tile 32x128.
__launch_bounds__(256, 4)
__global__ void k_gemm2(const signed char* __restrict__ hvb, const signed char* __restrict__ cT,
                        float* __restrict__ scores) {
    __shared__ signed char sA[64 * 128];    //  8 KB
    __shared__ signed char sB[256 * 128];   // 32 KB
    const int t = threadIdx.x;
    const int w = t >> 6, l = t & 63;

    const int orig = blockIdx.y * 4 + blockIdx.x;
    const int lid  = (orig & 7) * 128 + (orig >> 3);   // cpx = 1024/8 = 128
    const int bx = lid & 3, by = lid >> 2;

    const int m0 = by * 64, n0 = bx * 256;
    const int wm = (w >> 1) * 32, wn = (w & 1) * 128;  // wave tile 32x128
    const int lm = l & 15, kq = l >> 4;
    const int srow  = w * 8 + (l >> 3);                   // + i*32
    const int scol  = (((l & 7) ^ ((l >> 3) & 7))) * 16;  // swizzled source chunk (bytes)
    const int sbyte = w * 1024 + l * 16;                  // + i*4096

    intx4 acc[2][8] = {};

    for (int k0 = 0; k0 < HV_D; k0 += 128) {
        __syncthreads();
#pragma unroll
        for (int i = 0; i < 2; ++i)
            GLD16(hvb + (size_t)(m0 + srow + i * 32) * HV_D + k0 + scol,
                  (char*)sA + sbyte + i * 4096);
#pragma unroll
        for (int i = 0; i < 8; ++i)
            GLD16(cT + (size_t)(n0 + srow + i * 32) * HV_D + k0 + scol,
                  (char*)sB + sbyte + i * 4096);
        __syncthreads();
#pragma unroll
        for (int ks = 0; ks < 2; ++ks) {
            const int csw = ((ks * 4 + kq) ^ (lm & 7)) * 16;  // bytes
            intx4 b[8];
#pragma unroll
            for (int ns = 0; ns < 8; ++ns)
                b[ns] = *(const intx4*)&sB[(wn + ns * 16 + lm) * 128 + csw];
#pragma unroll
            for (int ms = 0; ms < 2; ++ms) {
                intx4 a = *(const intx4*)&sA[(wm + ms * 16 + lm) * 128 + csw];
#pragma unroll
                for (int ns = 0; ns < 8; ++ns)
                    acc[ms][ns] = __builtin_amdgcn_mfma_i32_16x16x64_i8(a, b[ns], acc[ms][ns], 0, 0, 0);
            }
        }
    }

#pragma unroll
    for (int ms = 0; ms < 2; ++ms) {
#pragma unroll
        for (int ns = 0; ns < 8; ++ns) {
            const int m = m0 + wm + ms * 16 + kq * 4;
            const int n = n0 + wn + ns * 16 + lm;
            if (n < NC) {
#pragma unroll
                for (int r = 0; r < 4; ++r)
                    __builtin_nontemporal_store((float)acc[ms][ns][r],
                                                &scores[(size_t)(m + r) * NC + n]);
            }
        }
    }
}

extern "C" void kernel_launch(void* const* d_in, const int* in_sizes, int n_in,
                              void* d_out, int out_size, void* d_ws, size_t ws_size,
                              hipStream_t stream) {
    const float* x    = (const float*)d_in[0];   // [16384][2048]
    const float* proj = (const float*)d_in[1];   // [2048][8192]
    const float* chv  = (const float*)d_in[2];   // [8192][1000]
    float* out    = (float*)d_out;
    float* scores = out;                          // [16384][1000]
    float* hv_out = out + (size_t)SCORES_N;       // [16384][8192]

    // workspace layout (total 310,378,496 B)
    char* ws = (char*)d_ws;
    _Float16*    xh  = (_Float16*)(ws);                         //  64 MiB
    _Float16*    xl  = (_Float16*)(ws + (size_t)67108864);      //  64 MiB
    _Float16*    pT  = (_Float16*)(ws + (size_t)134217728);     //  32 MiB
    signed char* cT  = (signed char*)(ws + (size_t)167772160);  //   8 MiB
    signed char* hvb = (signed char*)(ws + (size_t)176160768);  // 128 MiB

    k_split<<<(B_DIM * IN_D / 4) / 256, 256, 0, stream>>>(x, xh, xl);
    k_transpose_proj<<<dim3(HV_D / 64, IN_D / 64), 256, 0, stream>>>(proj, pT);
    k_pack_class<<<dim3(NCP / 64, HV_D / 64), 256, 0, stream>>>(chv, cT);
    // single gemm1 dispatch (~700us expected): lands in top-5 above the ~387us fills
    k_gemm1<<<dim3(HV_D / 256, B_DIM / 128), 512, 0, stream>>>(xh, xl, pT, hv_out, hvb);
    k_gemm2<<<dim3(NCP / 256, B_DIM / 64), 256, 0, stream>>>(hvb, cT, scores);
}

// Round 5
// 1661.144 us; speedup vs baseline: 1.2842x; 1.2842x over previous
//
#include <hip/hip_runtime.h>
#include <hip/hip_bf16.h>

typedef _Float16 half8  __attribute__((ext_vector_type(8)));
typedef _Float16 half4_t __attribute__((ext_vector_type(4)));
typedef float    floatx4 __attribute__((ext_vector_type(4)));
typedef int      intx4   __attribute__((ext_vector_type(4)));

#define B_DIM   16384
#define IN_D    2048
#define HV_D    8192
#define NC      1000
#define NCP     1024
#define SCORES_N (B_DIM * NC)

// async global->LDS, 16B per lane; LDS side is wave-uniform base + lane*16
#define GLD16(gp, lp) __builtin_amdgcn_global_load_lds( \
    (const __attribute__((address_space(1))) void*)(gp), \
    (__attribute__((address_space(3))) void*)(lp), 16, 0, 0)

// ---------- P1: Dekker split x (fp32) -> x_hi + x_lo (fp16), exact vs fp32 ----------
__global__ void k_split(const float* __restrict__ x, _Float16* __restrict__ xh,
                        _Float16* __restrict__ xl) {
    size_t i = (size_t)blockIdx.x * 256 + threadIdx.x;
    floatx4 v = ((const floatx4*)x)[i];
    half4_t h, l;
#pragma unroll
    for (int j = 0; j < 4; ++j) {
        _Float16 hh = (_Float16)v[j];
        h[j] = hh;
        l[j] = (_Float16)(v[j] - (float)hh);
    }
    ((half4_t*)xh)[i] = h;
    ((half4_t*)xl)[i] = l;
}

// ---------- P2: proj [K=2048][N=8192] fp32 -> projT [N][K] fp16 (LDS-tiled) ----------
__global__ void k_transpose_proj(const float* __restrict__ p, _Float16* __restrict__ pT) {
    __shared__ float tile[64][65];
    const int t = threadIdx.x;
    const int nt = blockIdx.x * 64;
    const int kt = blockIdx.y * 64;
    const int tr = t >> 4, tc = (t & 15) * 4;
#pragma unroll
    for (int s = 0; s < 4; ++s) {
        int r = tr + s * 16;
        floatx4 v = *(const floatx4*)&p[(size_t)(kt + r) * HV_D + nt + tc];
        tile[r][tc] = v[0]; tile[r][tc + 1] = v[1];
        tile[r][tc + 2] = v[2]; tile[r][tc + 3] = v[3];
    }
    __syncthreads();
#pragma unroll
    for (int s = 0; s < 4; ++s) {
        int rn = tr + s * 16;
        half4_t o;
#pragma unroll
        for (int j = 0; j < 4; ++j) o[j] = (_Float16)tile[tc + j][rn];
        *(half4_t*)&pT[(size_t)(nt + rn) * IN_D + kt + tc] = o;
    }
}

// ---------- P3: class_hv [8192][1000] fp32 -> classT [1024][8192] i8 ----------
__global__ void k_pack_class(const float* __restrict__ c, signed char* __restrict__ cT) {
    __shared__ signed char tile[64][68];
    const int t = threadIdx.x;
    const int nt = blockIdx.x * 64;
    const int kt = blockIdx.y * 64;
    const int nl = t & 63;
    const int n = nt + nl;
#pragma unroll
    for (int s = 0; s < 16; ++s) {
        const int kl = s * 4 + (t >> 6);
        signed char v = 0;
        if (n < NC) {
            float f = c[(size_t)(kt + kl) * NC + n];
            v = (f >= 0.f) ? (signed char)1 : (signed char)-1;
        }
        tile[kl][nl] = v;
    }
    __syncthreads();
    const int wn = t >> 2;
    const int wk = (t & 3) * 16;
    intx4 o;
    signed char* ob = (signed char*)&o;
#pragma unroll
    for (int j = 0; j < 16; ++j) ob[j] = tile[wk + j][wn];
    *(intx4*)&cT[(size_t)(nt + wn) * HV_D + kt + wk] = o;
}

// ---------- G1: hv = x@proj via fp16 hi/lo split, binarize, write fp32 + i8 ----------
// REVERTED to the R0-proven 1620us structure verbatim (49% MfmaUtil, 0 LDS conflicts,
// 2 blocks/CU whose mutual overlap hides the per-tile vmcnt drain). 128(M)x256(N),
// BK=64, 4 waves 2x2, wave tile 64x128, LDS 64KB single-buffered, __syncthreads drain.
// Lesson from R4's failed 8-phase port: 128KB dbuf -> 1 block/CU lockstep serializes
// LDS-read and MFMA sections and tripled per-MFMA LDS reads -> 34% MfmaUtil. The
// 2-block overlap IS the asset; do not trade it away.
__launch_bounds__(256, 2)
__global__ void k_gemm1(const _Float16* __restrict__ xh, const _Float16* __restrict__ xl,
                        const _Float16* __restrict__ pT,
                        float* __restrict__ hv_out, signed char* __restrict__ hvb,
                        int mbase) {
    __shared__ _Float16 sAh[128 * 64];   // 16 KB
    __shared__ _Float16 sAl[128 * 64];   // 16 KB
    __shared__ _Float16 sB [256 * 64];   // 32 KB
    const int t = threadIdx.x;
    const int w = t >> 6, l = t & 63;
    const int m0 = mbase + blockIdx.y * 128, n0 = blockIdx.x * 256;
    const int wm = (w >> 1) * 64, wn = (w & 1) * 128;
    const int lm = l & 15, kq = l >> 4;
    const int srow  = w * 8 + (l >> 3);                  // + i*32
    const int scol  = (((l & 7) ^ ((l >> 3) & 7))) * 8;  // swizzled source chunk (f16 units)
    const int sbyte = w * 1024 + l * 16;                 // + i*4096

    floatx4 acc[4][8] = {};

    for (int k0 = 0; k0 < IN_D; k0 += 64) {
        __syncthreads();
#pragma unroll
        for (int i = 0; i < 4; ++i) {
            const size_t ga = (size_t)(m0 + srow + i * 32) * IN_D + k0 + scol;
            const int lo = sbyte + i * 4096;
            GLD16(xh + ga, (char*)sAh + lo);
            GLD16(xl + ga, (char*)sAl + lo);
        }
#pragma unroll
        for (int i = 0; i < 8; ++i) {
            const size_t gb = (size_t)(n0 + srow + i * 32) * IN_D + k0 + scol;
            GLD16(pT + gb, (char*)sB + sbyte + i * 4096);
        }
        __syncthreads();
#pragma unroll
        for (int ks = 0; ks < 2; ++ks) {
            const int csw = ((ks * 4 + kq) ^ (lm & 7)) * 8;   // swizzled slot (f16 units)
            half8 b[8];
#pragma unroll
            for (int ns = 0; ns < 8; ++ns)
                b[ns] = *(const half8*)&sB[(wn + ns * 16 + lm) * 64 + csw];
#pragma unroll
            for (int ms = 0; ms < 4; ++ms) {
                half8 a = *(const half8*)&sAh[(wm + ms * 16 + lm) * 64 + csw];
#pragma unroll
                for (int ns = 0; ns < 8; ++ns)
                    acc[ms][ns] = __builtin_amdgcn_mfma_f32_16x16x32_f16(a, b[ns], acc[ms][ns], 0, 0, 0);
            }
#pragma unroll
            for (int ms = 0; ms < 4; ++ms) {
                half8 a = *(const half8*)&sAl[(wm + ms * 16 + lm) * 64 + csw];
#pragma unroll
                for (int ns = 0; ns < 8; ++ns)
                    acc[ms][ns] = __builtin_amdgcn_mfma_f32_16x16x32_f16(a, b[ns], acc[ms][ns], 0, 0, 0);
            }
        }
    }

    // epilogue: C/D layout col=lane&15, row=(lane>>4)*4+reg (plain stores, R0-exact)
#pragma unroll
    for (int ms = 0; ms < 4; ++ms) {
#pragma unroll
        for (int ns = 0; ns < 8; ++ns) {
            const int m = m0 + wm + ms * 16 + kq * 4;
            const int n = n0 + wn + ns * 16 + lm;
#pragma unroll
            for (int r = 0; r < 4; ++r) {
                const int pos = (acc[ms][ns][r] >= 0.f);
                const size_t o = (size_t)(m + r) * HV_D + n;
                hv_out[o] = pos ? 1.f : -1.f;
                hvb[o] = (signed char)(pos ? 1 : -1);
            }
        }
    }
}

// ---------- G2: scores = hv_bin @ class_hv, exact in i8 (K=8192) ----------
// THIS ROUND'S ONE EXPERIMENT: double-buffer + counted vmcnt (T3-minimum 2-phase).
// 64x256 block, BK=128, LDS (8+32)x2 = 80KB -> still 2 blocks/CU (the proven overlap
// regime). Per iter: stage 10 loads into buf^1, vmcnt(10) waits only for buf[cur]'s
// loads (issued a FULL iteration earlier -> near-zero stall), raw s_barrier pair,
// compute. Never vmcnt(0) in the loop; last tile peeled with vmcnt(0).
// Ledger: outstanding at wait = 10(cur) + 10(new) = 20 -> vmcnt(10) forces exactly
// cur's 10. Each wave's wait precedes barrier_B; all consumer ds_reads follow it.
__launch_bounds__(256, 2)
__global__ void k_gemm2(const signed char* __restrict__ hvb, const signed char* __restrict__ cT,
                        float* __restrict__ scores) {
    __shared__ signed char sA[2][64 * 128];    // 2 x  8 KB
    __shared__ signed char sB[2][256 * 128];   // 2 x 32 KB  => 80 KB total
    const int t = threadIdx.x;
    const int w = t >> 6, l = t & 63;

    // XCD swizzle: grid is (4, 256) = 1024 blocks, 1024 % 8 == 0 -> bijective.
    const int orig = blockIdx.y * 4 + blockIdx.x;
    const int lid  = (orig & 7) * 128 + (orig >> 3);   // cpx = 1024/8 = 128
    const int bx = lid & 3, by = lid >> 2;

    const int m0 = by * 64, n0 = bx * 256;
    const int wm = (w >> 1) * 32, wn = (w & 1) * 128;  // wave tile 32x128
    const int lm = l & 15, kq = l >> 4;
    const int srow  = w * 8 + (l >> 3);                   // + i*32
    const int scol  = (((l & 7) ^ ((l >> 3) & 7))) * 16;  // swizzled source chunk (bytes)
    const int sbyte = w * 1024 + l * 16;                  // + i*4096

    intx4 acc[2][8] = {};

#define G2_STAGE(buf, kt) do { \
    const int k0_ = (kt) * 128; \
    _Pragma("unroll") \
    for (int i = 0; i < 2; ++i) \
        GLD16(hvb + (size_t)(m0 + srow + i * 32) * HV_D + k0_ + scol, \
              (char*)&sA[buf][0] + sbyte + i * 4096); \
    _Pragma("unroll") \
    for (int i = 0; i < 8; ++i) \
        GLD16(cT + (size_t)(n0 + srow + i * 32) * HV_D + k0_ + scol, \
              (char*)&sB[buf][0] + sbyte + i * 4096); \
} while (0)

#define G2_COMPUTE(buf) do { \
    _Pragma("unroll") \
    for (int ks = 0; ks < 2; ++ks) { \
        const int csw = ((ks * 4 + kq) ^ (lm & 7)) * 16; \
        intx4 b[8]; \
        _Pragma("unroll") \
        for (int ns = 0; ns < 8; ++ns) \
            b[ns] = *(const intx4*)&sB[buf][(wn + ns * 16 + lm) * 128 + csw]; \
        _Pragma("unroll") \
        for (int ms = 0; ms < 2; ++ms) { \
            intx4 a = *(const intx4*)&sA[buf][(wm + ms * 16 + lm) * 128 + csw]; \
            _Pragma("unroll") \
            for (int ns = 0; ns < 8; ++ns) \
                acc[ms][ns] = __builtin_amdgcn_mfma_i32_16x16x64_i8(a, b[ns], acc[ms][ns], 0, 0, 0); \
        } \
    } \
} while (0)

    // prologue: k-tile 0 into buf0
    G2_STAGE(0, 0);

#pragma unroll 1
    for (int kt = 0; kt < 63; ++kt) {
        const int cur = kt & 1;
        __builtin_amdgcn_s_barrier();              // WAR: all waves done with buf[cur^1]
        if (cur == 0) G2_STAGE(1, kt + 1); else G2_STAGE(0, kt + 1);
        asm volatile("s_waitcnt vmcnt(10)" ::: "memory");   // force buf[cur]'s 10 loads
        __builtin_amdgcn_sched_barrier(0);
        __builtin_amdgcn_s_barrier();              // RAW: cur's data visible to all
        __builtin_amdgcn_sched_barrier(0);
        if (cur == 0) G2_COMPUTE(0); else G2_COMPUTE(1);
    }
    // peeled last tile: kt=63, cur=1
    __builtin_amdgcn_s_barrier();
    asm volatile("s_waitcnt vmcnt(0)" ::: "memory");
    __builtin_amdgcn_sched_barrier(0);
    __builtin_amdgcn_s_barrier();
    __builtin_amdgcn_sched_barrier(0);
    G2_COMPUTE(1);

#undef G2_STAGE
#undef G2_COMPUTE

#pragma unroll
    for (int ms = 0; ms < 2; ++ms) {
#pragma unroll
        for (int ns = 0; ns < 8; ++ns) {
            const int m = m0 + wm + ms * 16 + kq * 4;
            const int n = n0 + wn + ns * 16 + lm;
            if (n < NC) {
#pragma unroll
                for (int r = 0; r < 4; ++r)
                    __builtin_nontemporal_store((float)acc[ms][ns][r],
                                                &scores[(size_t)(m + r) * NC + n]);
            }
        }
    }
}

extern "C" void kernel_launch(void* const* d_in, const int* in_sizes, int n_in,
                              void* d_out, int out_size, void* d_ws, size_t ws_size,
                              hipStream_t stream) {
    const float* x    = (const float*)d_in[0];   // [16384][2048]
    const float* proj = (const float*)d_in[1];   // [2048][8192]
    const float* chv  = (const float*)d_in[2];   // [8192][1000]
    float* out    = (float*)d_out;
    float* scores = out;                          // [16384][1000]
    float* hv_out = out + (size_t)SCORES_N;       // [16384][8192]

    // workspace layout (total 310,378,496 B)
    char* ws = (char*)d_ws;
    _Float16*    xh  = (_Float16*)(ws);                         //  64 MiB
    _Float16*    xl  = (_Float16*)(ws + (size_t)67108864);      //  64 MiB
    _Float16*    pT  = (_Float16*)(ws + (size_t)134217728);     //  32 MiB
    signed char* cT  = (signed char*)(ws + (size_t)167772160);  //   8 MiB
    signed char* hvb = (signed char*)(ws + (size_t)176160768);  // 128 MiB

    k_split<<<(B_DIM * IN_D / 4) / 256, 256, 0, stream>>>(x, xh, xl);
    k_transpose_proj<<<dim3(HV_D / 64, IN_D / 64), 256, 0, stream>>>(proj, pT);
    k_pack_class<<<dim3(NCP / 64, HV_D / 64), 256, 0, stream>>>(chv, cT);
    // gemm1 as two half-M dispatches (R0-proven config)
    k_gemm1<<<dim3(HV_D / 256, B_DIM / 256), 256, 0, stream>>>(xh, xl, pT, hv_out, hvb, 0);
    k_gemm1<<<dim3(HV_D / 256, B_DIM / 256), 256, 0, stream>>>(xh, xl, pT, hv_out, hvb, B_DIM / 2);
    k_gemm2<<<dim3(NCP / 256, B_DIM / 64), 256, 0, stream>>>(hvb, cT, scores);
}